// Round 2
// baseline (70.882 us; speedup 1.0000x reference)
//
#include <hip/hip_runtime.h>
#include <hip/hip_bf16.h>
#include <cstdint>

// SKANLinear: out[b][o] = sum_i relu(w[o][i] * x_aug[b][i]),  x_aug = [x, 1]
// relu(p) = (p+|p|)/2, |w*x| = |w|*|x|  =>
//   out = x @ (w/2)^T + |x| @ (|w|/2)^T + relu(w[:,256])
// One bf16 GEMM, K=512 interleaved (x,|x|) vs (w/2,|w|/2).
//
// Round-2 structure: LDS-free, barrier-free streaming MFMA.
//  - prep_wfrag: w (f32, 263KB, L2-resident) -> Wfrag bf16 in per-lane
//    32x32x16 B-fragment order (lane-major): gemm B-load = 1 aligned short8.
//  - skan_gemm: wave tile 32x32 via mfma_f32_32x32x16_bf16; block = 2m x 2n
//    waves (64x64 tile); grid (128,4) = 512 blocks = 2/CU, 8 waves/CU.
//    x: float4 load -> in-reg (x,|x|) bf16 interleave. No LDS, no syncs.

typedef short short8 __attribute__((ext_vector_type(8)));   // 8 bf16 bits
typedef float f32x4  __attribute__((ext_vector_type(4)));
typedef float f32x16 __attribute__((ext_vector_type(16)));

#define NKK 32   // K-steps: 512 interleaved / 16 per MFMA

static __device__ __forceinline__ short f2bf(float f) {
    return __builtin_bit_cast(short, static_cast<__bf16>(f));
}

// ---- Kernel 1: weight -> B-fragment layout ----
// Wfrag[nblk][kk][lane][j] (short), nblk=col/32, kk=k-step, j=0..7:
//   col = nblk*32 + (lane&31), interleaved k = kk*16 + (lane>>5)*8 + j,
//   k=2c+s -> value = bf16( (s ? |w| : w)[col][c] * 0.5 ).
__global__ __launch_bounds__(64) void prep_wfrag(const float* __restrict__ w,
                                                 short* __restrict__ Wfrag) {
    const int nblk = blockIdx.x;            // 0..7
    const int kk   = blockIdx.y;            // 0..31
    const int lane = threadIdx.x;           // 0..63
    const int col  = nblk * 32 + (lane & 31);
    const int c0   = kk * 8 + (lane >> 5) * 4;       // 0..252 (col 256 = bias, excluded)
    const float* wr = w + (size_t)col * 257 + c0;    // rows are 257 f32 -> scalar loads
    short8 v;
#pragma unroll
    for (int t = 0; t < 4; ++t) {
        const float h = 0.5f * wr[t];
        v[2 * t]     = f2bf(h);
        v[2 * t + 1] = f2bf(__builtin_fabsf(h));
    }
    *reinterpret_cast<short8*>(Wfrag + ((size_t)(nblk * 32 + kk) * 64 + lane) * 8) = v;
}

// ---- Kernel 2: streaming MFMA GEMM ----
__global__ __launch_bounds__(256) void skan_gemm(const float* __restrict__ x,
                                                 const short* __restrict__ Wfrag,
                                                 const float* __restrict__ w,
                                                 float* __restrict__ out) {
    const int tid   = threadIdx.x;
    const int lane  = tid & 63;
    const int wid   = tid >> 6;
    const int wm    = wid & 1;               // 2x2 wave grid in the block
    const int wn    = wid >> 1;
    const int m0    = blockIdx.x * 64 + wm * 32;
    const int nf    = blockIdx.y * 2 + wn;   // 32-col fragment index, 0..7
    const int rlane = lane & 31;
    const int khalf = lane >> 5;

    // A: row = lane&31, k = (lane>>5)*8 + j  -> orig cols c0..c0+3, float4-aligned
    const float* xp = x + (size_t)(m0 + rlane) * 256 + khalf * 4;
    // B: lane-major prepped fragments, 512 shorts per k-step
    const short* bp = Wfrag + ((size_t)nf * NKK * 64 + lane) * 8;

    f32x16 acc0 = {}, acc1 = {};
#pragma unroll 4
    for (int kk = 0; kk < NKK; kk += 2) {
        const f32x4 v0 = *reinterpret_cast<const f32x4*>(xp + (size_t)kk * 8);
        const short8 b0 = *reinterpret_cast<const short8*>(bp + (size_t)kk * 512);
        const f32x4 v1 = *reinterpret_cast<const f32x4*>(xp + (size_t)(kk + 1) * 8);
        const short8 b1 = *reinterpret_cast<const short8*>(bp + (size_t)(kk + 1) * 512);
        short8 a0, a1;
#pragma unroll
        for (int t = 0; t < 4; ++t) {
            a0[2 * t]     = f2bf(v0[t]);
            a0[2 * t + 1] = f2bf(__builtin_fabsf(v0[t]));
            a1[2 * t]     = f2bf(v1[t]);
            a1[2 * t + 1] = f2bf(__builtin_fabsf(v1[t]));
        }
        acc0 = __builtin_amdgcn_mfma_f32_32x32x16_bf16(a0, b0, acc0, 0, 0, 0);
        acc1 = __builtin_amdgcn_mfma_f32_32x32x16_bf16(a1, b1, acc1, 0, 0, 0);
    }
    const f32x16 acc = acc0 + acc1;

    // C/D: col = lane&31, row = (reg&3) + 8*(reg>>2) + 4*(lane>>5)   [m74/m101]
    const int col  = nf * 32 + rlane;
    const float bias = __builtin_fmaxf(w[(size_t)col * 257 + 256], 0.0f);
    float* op = out + (size_t)(m0 + khalf * 4) * 256 + col;
#pragma unroll
    for (int r = 0; r < 16; ++r) {
        const int orow = (r & 3) + 8 * (r >> 2);
        op[(size_t)orow * 256] = acc[r] + bias;
    }
}

extern "C" void kernel_launch(void* const* d_in, const int* in_sizes, int n_in,
                              void* d_out, int out_size, void* d_ws, size_t ws_size,
                              hipStream_t stream) {
    const float* x = (const float*)d_in[0];   // [8192][256] f32
    const float* w = (const float*)d_in[1];   // [256][257] f32
    float* out = (float*)d_out;               // [8192][256] f32

    short* Wfrag = (short*)d_ws;              // 8*32*64*8*2 = 262144 B

    prep_wfrag<<<dim3(8, 32), dim3(64), 0, stream>>>(w, Wfrag);
    skan_gemm<<<dim3(128, 4), dim3(256), 0, stream>>>(x, Wfrag, w, out);
}